// Round 11
// baseline (848.192 us; speedup 1.0000x reference)
//
#include <hip/hip_runtime.h>

#define IMG  512
#define TR   48           // output tile rows per block
#define TC   112          // output tile cols per block
#define RH   8            // halo = max steps per round
#define RLW  132          // SoA row stride dwords: s0'[33] s1[32] s2[32] s3'[33] +2 pad
#define PR   66           // phys rows: logical -1..64

typedef float v2 __attribute__((ext_vector_type(2)));

__device__ __forceinline__ float mapf(float g) {
    float t = 3.9f * g;
    return t - t * g;     // R*g*(1-g)
}

// SoA col mapping (buffer cols -1..128):
//   col 4j+0 -> off j ; col 4j+1 -> off 33+j ; col 4j+2 -> off 65+j ;
//   col 4j+3 -> off 98+j ; left-ext col -1 -> off 97 ; right-ext col 128 -> off 32.
// Window col 4pj-1+i, i=0..5 -> offsets {97+pj, pj, 33+pj, 65+pj, 98+pj, 1+pj}.

// One temporal round: init M=map(src), run `steps` CML steps, store grid to
// dst (clipped if do_clip). 512 threads, each owns a 4-wide x 4-tall patch
// computed as TWO ROW-PAIRS with packed <2 x float> math (v_pk_fma_f32):
// row-pair sets {r-1,r} and {r+1,r+2} load directly into VGPR-pair halves
// (2 ds_read_b32 each, zero assembly); middle set = {top.hi, bot.lo}.
// Pair 2 reuses pair 1's bottom set -> LDS reads stay 36/step (conflict-free
// SoA), conv VALU halves: 144 fma -> 72 pk_fma.
__global__ __launch_bounds__(512) void cml_round(
    const float* __restrict__ src,
    const float* __restrict__ drv,
    const float* __restrict__ Kw,
    float* __restrict__ dst,
    int steps, int do_clip)
{
    __shared__ float B[PR * RLW];      // 34.8 KiB -> 4 blocks/CU

    const int tid = threadIdx.x;
    const int bid = blockIdx.x;
    const int bc  = bid / 55;               // image*channel index
    const int tl  = bid % 55;               // 11 row-strips x 5 col-tiles
    const int gy0 = (tl / 5) * TR - RH;     // logical buffer row 0 -> gy0
    const int gx0 = (tl % 5) * TC - RH;     // multiple of 4
    const float* __restrict__ simg = src + (size_t)bc * (IMG*IMG);
    const float* __restrict__ dimg = drv + (size_t)bc * (IMG*IMG);
    float*       __restrict__ oimg = dst + (size_t)bc * (IMG*IMG);

    // Folded 3x3 kernel: K' = (0.85*0.3)*K + (0.85*0.7)*delta_center (uniform)
    float kk[9];
    {
        const float c2 = 0.85f * 0.3f;
        const float* kp = Kw + (bc & 3) * 9;
#pragma unroll
        for (int q = 0; q < 9; q++) kk[q] = c2 * kp[q];
        kk[4] += 0.85f * 0.7f;
    }

    const int pj  = tid & 31;               // col patch: owned cols 4pj..4pj+3
    const int pi  = tid >> 5;               // row band:  owned rows 4pi..4pi+3
    const int y0  = pi * 4;
    const int gxb = gx0 + pj * 4;           // global col of owned float4
    const float fxc = ((unsigned)gxb < IMG) ? 1.0f : 0.0f;

    // boundary flag pairs (rows r0..r0+3), hoisted
    v2 fp1, fp2;
    fp1.x = (((unsigned)(gy0 + y0 + 0) < IMG) ? 1.0f : 0.0f) * fxc;
    fp1.y = (((unsigned)(gy0 + y0 + 1) < IMG) ? 1.0f : 0.0f) * fxc;
    fp2.x = (((unsigned)(gy0 + y0 + 2) < IMG) ? 1.0f : 0.0f) * fxc;
    fp2.y = (((unsigned)(gy0 + y0 + 3) < IMG) ? 1.0f : 0.0f) * fxc;

    // beta*drive, pre-paired across rows: dp1[k]={r0,r0+1}, dp2[k]={r0+2,r0+3}
    v2 dp1[4], dp2[4];
    {
        float4 dr[4];
#pragma unroll
        for (int rr = 0; rr < 4; rr++) {
            const int gy = gy0 + y0 + rr;
            float4 dv = make_float4(0.f, 0.f, 0.f, 0.f);
            if ((unsigned)gy < IMG && (unsigned)gxb < IMG)
                dv = *(const float4*)(dimg + gy*IMG + gxb);
            dr[rr] = dv;
        }
        dp1[0].x = 0.15f*dr[0].x; dp1[0].y = 0.15f*dr[1].x;
        dp1[1].x = 0.15f*dr[0].y; dp1[1].y = 0.15f*dr[1].y;
        dp1[2].x = 0.15f*dr[0].z; dp1[2].y = 0.15f*dr[1].z;
        dp1[3].x = 0.15f*dr[0].w; dp1[3].y = 0.15f*dr[1].w;
        dp2[0].x = 0.15f*dr[2].x; dp2[0].y = 0.15f*dr[3].x;
        dp2[1].x = 0.15f*dr[2].y; dp2[1].y = 0.15f*dr[3].y;
        dp2[2].x = 0.15f*dr[2].z; dp2[2].y = 0.15f*dr[3].z;
        dp2[3].x = 0.15f*dr[2].w; dp2[3].y = 0.15f*dr[3].w;
    }

    // Init: B = map(src) over phys rows 0..65 (logical -1..64), SoA layout.
    for (int u = tid; u < PR * 32; u += 512) {
        const int r = u >> 5;
        const int p = u & 31;
        const int gy  = gy0 + r - 1;
        const int gxq = gx0 + p * 4;
        const bool rowok = (unsigned)gy < IMG;
        float4 v = make_float4(0.f, 0.f, 0.f, 0.f);
        if (rowok && (unsigned)gxq < IMG)
            v = *(const float4*)(simg + gy*IMG + gxq);   // gxq<=508: no row cross
        float* row = B + r * RLW;
        row[p]      = mapf(v.x);
        row[33 + p] = mapf(v.y);
        row[65 + p] = mapf(v.z);
        row[98 + p] = mapf(v.w);
        if (p == 0) {
            float e = (rowok && (unsigned)(gx0 - 1) < IMG)
                    ? simg[gy*IMG + gx0 - 1] : 0.f;
            row[97] = mapf(e);
        }
        if (p == 31) {
            float e = (rowok && (unsigned)(gx0 + 128) < IMG)
                    ? simg[gy*IMG + gx0 + 128] : 0.f;
            row[32] = mapf(e);
        }
    }
    __syncthreads();

    const int off0 = 97 + pj, off1 = pj, off2 = 33 + pj,
              off3 = 65 + pj, off4 = 98 + pj, off5 = 1 + pj;

    v2 s1[4], s2[4];
#pragma unroll 1
    for (int step = 0; step < steps - 1; step++) {
        const float* r0 = B + y0 * RLW;     // phys y0 = logical r0-1
        const int off[6] = {off0, off1, off2, off3, off4, off5};

        // ---- row-pair 1: output rows r0, r0+1 ----
        v2 T[6], Bo[6], M1[6];
#pragma unroll
        for (int c = 0; c < 6; c++) {
            T[c].x  = r0[off[c]];                 // row r0-1
            T[c].y  = r0[RLW + off[c]];           // row r0
            Bo[c].x = r0[2*RLW + off[c]];         // row r0+1
            Bo[c].y = r0[3*RLW + off[c]];         // row r0+2
            M1[c].x = T[c].y;  M1[c].y = Bo[c].x; // rows {r0, r0+1}
        }
#pragma unroll
        for (int k = 0; k < 4; k++) {
            v2 s = dp1[k];
            s += kk[0]*T[k]  + kk[1]*T[k+1]  + kk[2]*T[k+2];
            s += kk[3]*M1[k] + kk[4]*M1[k+1] + kk[5]*M1[k+2];
            s += kk[6]*Bo[k] + kk[7]*Bo[k+1] + kk[8]*Bo[k+2];
            v2 t = 3.9f * s;
            s1[k] = (t - t*s) * fp1;
        }
        // ---- row-pair 2: output rows r0+2, r0+3 (top set = Bo, reused) ----
        v2 B2[6], M2[6];
#pragma unroll
        for (int c = 0; c < 6; c++) {
            B2[c].x = r0[4*RLW + off[c]];         // row r0+3
            B2[c].y = r0[5*RLW + off[c]];         // row r0+4
            M2[c].x = Bo[c].y; M2[c].y = B2[c].x; // rows {r0+2, r0+3}
        }
#pragma unroll
        for (int k = 0; k < 4; k++) {
            v2 s = dp2[k];
            s += kk[0]*Bo[k] + kk[1]*Bo[k+1] + kk[2]*Bo[k+2];
            s += kk[3]*M2[k] + kk[4]*M2[k+1] + kk[5]*M2[k+2];
            s += kk[6]*B2[k] + kk[7]*B2[k+1] + kk[8]*B2[k+2];
            v2 t = 3.9f * s;
            s2[k] = (t - t*s) * fp2;
        }
        __syncthreads();   // all reads done before any write (WAR)
        {
            float* w = B + (y0 + 1) * RLW;        // phys = logical+1
            const int wo[4] = {pj, 33 + pj, 65 + pj, 98 + pj};
#pragma unroll
            for (int k = 0; k < 4; k++) {
                w[wo[k]]           = s1[k].x;     // row r0
                w[RLW + wo[k]]     = s1[k].y;     // row r0+1
                w[2*RLW + wo[k]]   = s2[k].x;     // row r0+2
                w[3*RLW + wo[k]]   = s2[k].y;     // row r0+3
            }
        }
        __syncthreads();   // writes done before next step's reads (RAW)
    }

    // Final step of the round: compute grid (no map/flag), store interior.
    {
        const float* r0 = B + y0 * RLW;
        const int off[6] = {off0, off1, off2, off3, off4, off5};
        v2 T[6], Bo[6], M1[6];
#pragma unroll
        for (int c = 0; c < 6; c++) {
            T[c].x  = r0[off[c]];
            T[c].y  = r0[RLW + off[c]];
            Bo[c].x = r0[2*RLW + off[c]];
            Bo[c].y = r0[3*RLW + off[c]];
            M1[c].x = T[c].y;  M1[c].y = Bo[c].x;
        }
#pragma unroll
        for (int k = 0; k < 4; k++) {
            v2 s = dp1[k];
            s += kk[0]*T[k]  + kk[1]*T[k+1]  + kk[2]*T[k+2];
            s += kk[3]*M1[k] + kk[4]*M1[k+1] + kk[5]*M1[k+2];
            s += kk[6]*Bo[k] + kk[7]*Bo[k+1] + kk[8]*Bo[k+2];
            s1[k] = s;
        }
        v2 B2[6], M2[6];
#pragma unroll
        for (int c = 0; c < 6; c++) {
            B2[c].x = r0[4*RLW + off[c]];
            B2[c].y = r0[5*RLW + off[c]];
            M2[c].x = Bo[c].y; M2[c].y = B2[c].x;
        }
#pragma unroll
        for (int k = 0; k < 4; k++) {
            v2 s = dp2[k];
            s += kk[0]*Bo[k] + kk[1]*Bo[k+1] + kk[2]*Bo[k+2];
            s += kk[3]*M2[k] + kk[4]*M2[k+1] + kk[5]*M2[k+2];
            s += kk[6]*B2[k] + kk[7]*B2[k+1] + kk[8]*B2[k+2];
            s2[k] = s;
        }
    }
    // Valid region: rows [8,56) -> pi in [2,13]; cols [8,120) -> pj in [2,29].
    if (pi >= 2 && pi <= 13 && pj >= 2 && pj <= 29) {
        float rowv[4][4];
#pragma unroll
        for (int k = 0; k < 4; k++) {
            rowv[0][k] = s1[k].x;  rowv[1][k] = s1[k].y;
            rowv[2][k] = s2[k].x;  rowv[3][k] = s2[k].y;
        }
#pragma unroll
        for (int rr = 0; rr < 4; rr++) {
            const int gy = gy0 + y0 + rr;       // >= 0 (pi>=2)
            if (gy < IMG && gxb + 3 < IMG) {
                float4 v = make_float4(rowv[rr][0], rowv[rr][1],
                                       rowv[rr][2], rowv[rr][3]);
                if (do_clip) {
                    v.x = fminf(fmaxf(v.x, 1e-4f), 1.0f - 1e-4f);
                    v.y = fminf(fmaxf(v.y, 1e-4f), 1.0f - 1e-4f);
                    v.z = fminf(fmaxf(v.z, 1e-4f), 1.0f - 1e-4f);
                    v.w = fminf(fmaxf(v.w, 1e-4f), 1.0f - 1e-4f);
                }
                *(float4*)(oimg + gy*IMG + gxb) = v;
            }
        }
    }
}

// ---------------- Fallback: single-kernel 15-step version (Round-4) ----------
#define TILE  128
#define OFF_Y 16
#define OFF_X 18
#define BUFY  160
#define BUFX  164
#define LW    172
#define NP    1014

__device__ __forceinline__ void read_row6(const float* __restrict__ p, int xw,
                                          float* m) {
    const float4 mid = *(const float4*)(p + xw + 4);
    m[0] = p[xw + 3];
    m[1] = mid.x; m[2] = mid.y; m[3] = mid.z; m[4] = mid.w;
    m[5] = p[xw + 8];
}

__global__ __launch_bounds__(1024, 4) void cml_fused(
    const float* __restrict__ drive,
    const float* __restrict__ Kw,
    float* __restrict__ out)
{
    __shared__ float lds[BUFY * LW];
    const int tid = threadIdx.x;
    const int bid = blockIdx.x;
    const int bc  = bid >> 4;
    const int tl  = bid & 15;
    const int gy0 = (tl >> 2) * TILE - OFF_Y;
    const int gx0 = (tl & 3)  * TILE - OFF_X;
    const float* __restrict__ img  = drive + (size_t)bc * (IMG*IMG);
    float*       __restrict__ oimg = out   + (size_t)bc * (IMG*IMG);
    float kk[9];
    {
        const float c2 = 0.85f * 0.3f;
        const float* kp = Kw + (bc & 3) * 9;
#pragma unroll
        for (int q = 0; q < 9; q++) kk[q] = c2 * kp[q];
        kk[4] += 0.85f * 0.7f;
    }
    const int t2 = tid < NP ? tid : NP - 1;
    const int pi = t2 / 39;
    const int pj = t2 - pi * 39;
    const int y0 = 2 + 6 * pi;
    const int xw = 4 * pj;
    float dvs[24], fx[4], fy[6];
#pragma unroll
    for (int k = 0; k < 4; k++)
        fx[k] = ((unsigned)(gx0 + xw + 4 + k) < IMG) ? 1.0f : 0.0f;
#pragma unroll
    for (int rr = 0; rr < 6; rr++) {
        const int gy = gy0 + y0 + rr;
        fy[rr] = ((unsigned)gy < IMG) ? 1.0f : 0.0f;
#pragma unroll
        for (int k = 0; k < 4; k++) {
            const int gx = gx0 + xw + 4 + k;
            dvs[rr*4+k] = (((unsigned)gy < IMG) && ((unsigned)gx < IMG))
                        ? 0.15f * img[gy*IMG + gx] : 0.0f;
        }
    }
    for (int u = tid; u < BUFY * (LW/2); u += 1024) {
        const int yy = u / (LW/2);
        const int xx = (u - yy * (LW/2)) * 2;
        const int gy = gy0 + yy;
        const int gxb = gx0 + xx;
        float2 v = make_float2(0.f, 0.f);
        if (xx < BUFX && (unsigned)gy < IMG && (unsigned)gxb < IMG)
            v = *(const float2*)(img + gy*IMG + gxb);
        v.x = mapf(v.x); v.y = mapf(v.y);
        *(float2*)(lds + yy*LW + xx) = v;
    }
    __syncthreads();
    float st[24];
#pragma unroll 1
    for (int step = 0; step < 14; step++) {
        {
            float a[6], b[6], c[6];
            const float* p = lds + (y0 - 1) * LW;
            read_row6(p, xw, a);  p += LW;
            read_row6(p, xw, b);
#pragma unroll
            for (int rr = 0; rr < 6; rr++) {
                p += LW;
                read_row6(p, xw, c);
                const float fyr = fy[rr];
#pragma unroll
                for (int k = 0; k < 4; k++) {
                    float s = dvs[rr*4+k];
                    s += kk[0]*a[k] + kk[1]*a[k+1] + kk[2]*a[k+2];
                    s += kk[3]*b[k] + kk[4]*b[k+1] + kk[5]*b[k+2];
                    s += kk[6]*c[k] + kk[7]*c[k+1] + kk[8]*c[k+2];
                    const float t = 3.9f * s;
                    st[rr*4+k] = (t - t*s) * fyr * fx[k];
                }
#pragma unroll
                for (int q = 0; q < 6; q++) { a[q] = b[q]; b[q] = c[q]; }
            }
        }
        __syncthreads();
        {
            float* w = lds + y0 * LW + xw + 4;
#pragma unroll
            for (int rr = 0; rr < 6; rr++) {
                *(float4*)w = make_float4(st[rr*4+0], st[rr*4+1],
                                          st[rr*4+2], st[rr*4+3]);
                w += LW;
            }
        }
        __syncthreads();
    }
    {
        float a[6], b[6], c[6];
        const float* p = lds + (y0 - 1) * LW;
        read_row6(p, xw, a);  p += LW;
        read_row6(p, xw, b);
#pragma unroll
        for (int rr = 0; rr < 6; rr++) {
            p += LW;
            read_row6(p, xw, c);
#pragma unroll
            for (int k = 0; k < 4; k++) {
                float s = dvs[rr*4+k];
                s += kk[0]*a[k] + kk[1]*a[k+1] + kk[2]*a[k+2];
                s += kk[3]*b[k] + kk[4]*b[k+1] + kk[5]*b[k+2];
                s += kk[6]*c[k] + kk[7]*c[k+1] + kk[8]*c[k+2];
                st[rr*4+k] = fminf(fmaxf(s, 1e-4f), 1.0f - 1e-4f);
            }
#pragma unroll
            for (int q = 0; q < 6; q++) { a[q] = b[q]; b[q] = c[q]; }
        }
    }
#pragma unroll
    for (int rr = 0; rr < 6; rr++) {
        const int r = y0 + rr;
        if (r >= OFF_Y && r < OFF_Y + TILE) {
#pragma unroll
            for (int h = 0; h < 2; h++) {
                const int col = xw + 4 + 2*h;
                if (col >= OFF_X && col + 1 < OFF_X + TILE) {
                    *(float2*)(oimg + (size_t)(gy0 + r) * IMG + (gx0 + col)) =
                        make_float2(st[rr*4 + 2*h], st[rr*4 + 2*h + 1]);
                }
            }
        }
    }
}

extern "C" void kernel_launch(void* const* d_in, const int* in_sizes, int n_in,
                              void* d_out, int out_size, void* d_ws, size_t ws_size,
                              hipStream_t stream)
{
    const float* drive = (const float*)d_in[0];
    const float* Kw    = (const float*)d_in[1];
    float* out         = (float*)d_out;
    const size_t need  = (size_t)256 * IMG * IMG * sizeof(float);  // 256 MiB

    if (ws_size >= need) {
        float* g8 = (float*)d_ws;
        // 256 images x 55 tiles (11 row-strips x 5 col-tiles) = 14080 blocks
        cml_round<<<dim3(14080), dim3(512), 0, stream>>>(drive, drive, Kw, g8, 8, 0);
        cml_round<<<dim3(14080), dim3(512), 0, stream>>>(g8, drive, Kw, out, 7, 1);
    } else {
        cml_fused<<<dim3(4096), dim3(1024), 0, stream>>>(drive, Kw, out);
    }
}